// Round 20
// baseline (323.193 us; speedup 1.0000x reference)
//
#include <hip/hip_runtime.h>

#define NN 50000
#define NE 800000
#define HD 128

typedef short short8 __attribute__((ext_vector_type(8)));
typedef float floatx4 __attribute__((ext_vector_type(4)));
typedef float floatx16 __attribute__((ext_vector_type(16)));

static __device__ __forceinline__ unsigned short f2bf(float f) {
    unsigned int u = __float_as_uint(f);
    unsigned int lsb = (u >> 16) & 1u;
    u += 0x7fffu + lsb;
    return (unsigned short)(u >> 16);
}

static __device__ __forceinline__ float bf2f(unsigned short h) {
    return __uint_as_float((unsigned int)h << 16);
}

// HW packed f32->bf16 (RNE), 2 elems/instr; lo=src0, hi=src1.
static __device__ __forceinline__ short8 pack2(float4 a, float4 b) {
    union { unsigned int u[4]; short8 s; } r;
    asm("v_cvt_pk_bf16_f32 %0, %1, %2" : "=v"(r.u[0]) : "v"(a.x), "v"(a.y));
    asm("v_cvt_pk_bf16_f32 %0, %1, %2" : "=v"(r.u[1]) : "v"(a.z), "v"(a.w));
    asm("v_cvt_pk_bf16_f32 %0, %1, %2" : "=v"(r.u[2]) : "v"(b.x), "v"(b.y));
    asm("v_cvt_pk_bf16_f32 %0, %1, %2" : "=v"(r.u[3]) : "v"(b.z), "v"(b.w));
    return r.s;
}

static __device__ __forceinline__ floatx4 mfma16x16x32(short8 a, short8 b, floatx4 c) {
    asm("v_mfma_f32_16x16x32_bf16 %0, %1, %2, %0" : "+v"(c) : "v"(a), "v"(b));
    return c;
}

static __device__ __forceinline__ floatx16 mfma32x32x16(short8 a, short8 b, floatx16 c) {
    asm("v_mfma_f32_32x32x16_bf16 %0, %1, %2, %0" : "+v"(c) : "v"(a), "v"(b));
    return c;
}

// Hazard guards: inline-asm MFMA is invisible to LLVM's GCNHazardRecognizer.
#define NOPGUARD_INIT8(A) asm volatile("s_nop 3" \
  : "+v"(A[0]),"+v"(A[1]),"+v"(A[2]),"+v"(A[3]),"+v"(A[4]),"+v"(A[5]),"+v"(A[6]),"+v"(A[7]))
#define NOPGUARD8(A) asm volatile("s_nop 7\ns_nop 7" \
  : "+v"(A[0]),"+v"(A[1]),"+v"(A[2]),"+v"(A[3]),"+v"(A[4]),"+v"(A[5]),"+v"(A[6]),"+v"(A[7]))
#define NOPGUARD_INIT4x16(A) asm volatile("s_nop 7" \
  : "+v"(A[0]),"+v"(A[1]),"+v"(A[2]),"+v"(A[3]))
#define NOPGUARD4x16(A) asm volatile("s_nop 7\ns_nop 7\ns_nop 7" \
  : "+v"(A[0]),"+v"(A[1]),"+v"(A[2]),"+v"(A[3]))

// Wave-local LDS fence.
#define WAVE_LDS_FENCE() asm volatile("s_waitcnt lgkmcnt(0)" ::: "memory")

// ---------------- fused prep: x-cast + hist + ea-cast + weight packing ----------------
// t in [0, 800000): cast one 8-elem x chunk AND one hist atomic (counts==NE).
// t in [800000, 4000000): cast one 8-elem ea chunk.
// t in [4000000, 4106496): pack one weight element (W1q/W2q 32x32 B-layout,
// U1p/U2p 16x16 B-layout).
__global__ void prep_kernel(const float* __restrict__ x, unsigned short* __restrict__ xbuf,
                            const float* __restrict__ ea, unsigned short* __restrict__ eabuf,
                            const int* __restrict__ ei, int* __restrict__ counts,
                            const float* __restrict__ mW1, const float* __restrict__ mW2,
                            const float* __restrict__ uW1, const float* __restrict__ uW2,
                            unsigned short* __restrict__ W1q, unsigned short* __restrict__ W2q,
                            unsigned short* __restrict__ U1p, unsigned short* __restrict__ U2p) {
    int t = blockIdx.x * 256 + threadIdx.x;
    if (t < 800000) {
        float4 a = *reinterpret_cast<const float4*>(x + (size_t)t * 8);
        float4 b = *reinterpret_cast<const float4*>(x + (size_t)t * 8 + 4);
        *reinterpret_cast<short8*>(xbuf + (size_t)t * 8) = pack2(a, b);
        atomicAdd(&counts[ei[NE + t]], 1);
    } else if (t < 4000000) {
        int u = t - 800000;
        float4 a = *reinterpret_cast<const float4*>(ea + (size_t)u * 8);
        float4 b = *reinterpret_cast<const float4*>(ea + (size_t)u * 8 + 4);
        *reinterpret_cast<short8*>(eabuf + (size_t)u * 8) = pack2(a, b);
    } else {
        int w = t - 4000000;
        if (w < 40960) {
            int i = w;
            int j = i & 7, lane = (i >> 3) & 63, n = (i >> 9) & 3, s = i >> 11;
            int k = s * 16 + ((lane >> 5) << 3) + j;
            int c = n * 32 + (lane & 31);
            W1q[i] = f2bf((k < 291) ? mW1[k * 128 + c] : 0.0f);
        } else if (w < 57344) {
            int i = w - 40960;
            int j = i & 7, lane = (i >> 3) & 63, n = (i >> 9) & 3, s = i >> 11;
            int k = s * 16 + ((lane >> 5) << 3) + j;
            int c = n * 32 + (lane & 31);
            W2q[i] = f2bf(mW2[k * 128 + c]);
        } else if (w < 90112) {
            int i = w - 57344;
            int j = i & 7, lane = (i >> 3) & 63, n = (i >> 9) & 7, kk = i >> 12;
            int k = kk * 32 + ((lane >> 4) << 3) + j;
            int c = n * 16 + (lane & 15);
            U1p[i] = f2bf(uW1[k * 128 + c]);
        } else if (w < 106496) {
            int i = w - 90112;
            int j = i & 7, lane = (i >> 3) & 63, n = (i >> 9) & 7, kk = i >> 12;
            int k = kk * 32 + ((lane >> 4) << 3) + j;
            int c = n * 16 + (lane & 15);
            U2p[i] = f2bf(uW2[k * 128 + c]);
        }
    }
}

// ---------------- single-launch exclusive prefix scan over counts ----------------
// One 1024-thread block loops 49 chunks; running offset carried in LDS.
__global__ __launch_bounds__(1024)
void scan_kernel(const int* __restrict__ counts, int* __restrict__ partial) {
    __shared__ int wsum[16];
    __shared__ int running;
    int tid = threadIdx.x;
    int lane = tid & 63, w = tid >> 6;
    if (tid == 0) running = 0;
    __syncthreads();
    for (int base = 0; base < NN; base += 1024) {
        int gid = base + tid;
        int v = (gid < NN) ? counts[gid] : 0;
        int s = v;
        #pragma unroll
        for (int o = 1; o < 64; o <<= 1) { int t = __shfl_up(s, o); if (lane >= o) s += t; }
        if (lane == 63) wsum[w] = s;
        __syncthreads();
        if (w == 0 && lane < 16) {
            int t = wsum[lane];
            #pragma unroll
            for (int o = 1; o < 16; o <<= 1) { int u = __shfl_up(t, o); if (lane >= o) t += u; }
            wsum[lane] = t;
        }
        __syncthreads();
        int wbase = (w > 0) ? wsum[w - 1] : 0;
        if (gid < NN) partial[gid] = running + wbase + s - v;
        __syncthreads();
        if (tid == 0) running += wsum[15];
        __syncthreads();
    }
}

// ---------------- scatter: epack64 (eid|src<<20|dst<<36) + bf16 rel ----------------
__global__ void scatter_kernel(const int* __restrict__ ei, const int* __restrict__ partial,
                               int* __restrict__ cursor, const float* __restrict__ cd,
                               unsigned long long* __restrict__ epack,
                               uint2* __restrict__ relb) {
    int e = blockIdx.x * 256 + threadIdx.x;
    if (e < NE) {
        int d = ei[NE + e];
        int s = ei[e];
        int pos = partial[d] + atomicAdd(&cursor[d], 1);
        epack[pos] = (unsigned long long)e
                   | ((unsigned long long)s << 20)
                   | ((unsigned long long)d << 36);
        float r0 = cd[d * 3 + 0] - cd[s * 3 + 0];
        float r1 = cd[d * 3 + 1] - cd[s * 3 + 1];
        float r2 = cd[d * 3 + 2] - cd[s * 3 + 2];
        uint2 rr;
        asm("v_cvt_pk_bf16_f32 %0, %1, %2" : "=v"(rr.x) : "v"(r0), "v"(r1));
        asm("v_cvt_pk_bf16_f32 %0, %1, %2" : "=v"(rr.y) : "v"(r2), "v"(0.0f));
        relb[pos] = rr;
    }
}

// ---------------- message MLP (unchanged from r19: 160us, at its ledgered floor) ----------------
__global__ __launch_bounds__(256, 4)
void msg_kernel(const unsigned short* __restrict__ xb, const unsigned short* __restrict__ eab,
                const unsigned long long* __restrict__ epack, const uint2* __restrict__ relb,
                const unsigned short* __restrict__ W1q, const float* __restrict__ mb1,
                const float* __restrict__ mb2,
                float* __restrict__ aggr) {
    __shared__ unsigned short sH[128 * 136];   // hidden tile, then bf16 out tile
    __shared__ unsigned short sW[2048];        // one 4 KB weight chunk
    __shared__ int sDst[128];

    const int tid = threadIdx.x;
    const int lane = tid & 63;
    const int wid = tid >> 6;
    const int lr31 = lane & 31;
    const int half = lane >> 5;
    const int wrow = wid * 32 + lr31;
    const int eidx = blockIdx.x * 128 + wrow;

    const unsigned long long p = epack[eidx];
    const int eid = (int)(p & 0xFFFFFull);
    const int src = (int)((p >> 20) & 0xFFFFull);
    const int dst = (int)(p >> 36);
    if (half == 0) sDst[wrow] = dst;

    const unsigned short* xs = xb + (size_t)src * 128 + half * 8;
    const unsigned short* xd = xb + (size_t)dst * 128 + half * 8;
    const unsigned short* epr = eab + (size_t)eid * 32 + half * 8;
    const uint2 rr = relb[eidx];

    // Prefetch weight chunk 0 (W2 chunks contiguous at short-offset 40960).
    short8 wpre = *reinterpret_cast<const short8*>(W1q + tid * 8);

    floatx16 acc[4];
    #pragma unroll
    for (int n = 0; n < 4; ++n)
        #pragma unroll
        for (int q = 0; q < 16; ++q) acc[n][q] = 0.0f;
    NOPGUARD_INIT4x16(acc);

    #pragma unroll
    for (int s = 0; s < 19; ++s) {
        *reinterpret_cast<short8*>(sW + tid * 8) = wpre;
        __syncthreads();
        {
            int nc = (s < 18) ? (s + 1) * 2048 : 40960;
            wpre = *reinterpret_cast<const short8*>(W1q + nc + tid * 8);
        }
        short8 a;
        if (s < 8) {
            a = *reinterpret_cast<const short8*>(xs + s * 16);
        } else if (s < 16) {
            a = *reinterpret_cast<const short8*>(xd + (s - 8) * 16);
        } else if (s < 18) {
            a = *reinterpret_cast<const short8*>(epr + (s - 16) * 16);
        } else {
            union { unsigned int u[4]; short8 s8; } a9;
            a9.u[0] = (half == 0) ? rr.x : 0u;
            a9.u[1] = (half == 0) ? rr.y : 0u;
            a9.u[2] = 0u; a9.u[3] = 0u;
            a = a9.s8;
        }
        #pragma unroll
        for (int n = 0; n < 4; ++n) {
            short8 b = *reinterpret_cast<const short8*>(sW + n * 512 + lane * 8);
            acc[n] = mfma32x32x16(a, b, acc[n]);
        }
        __syncthreads();
    }
    NOPGUARD4x16(acc);

    unsigned int hm32;
    {
        bool head = false;
        if (lane < 32) {
            int r = wid * 32 + lane;
            head = (lane == 0) || (sDst[r] != sDst[r - 1]);
        }
        unsigned long long m = __ballot(head);
        hm32 = (unsigned int)(m & 0xFFFFFFFFull);
    }

    #pragma unroll
    for (int n = 0; n < 4; ++n) {
        float bias = mb1[n * 32 + lr31];
        #pragma unroll
        for (int q = 0; q < 16; ++q) {
            int crow = (q & 3) + 8 * (q >> 2) + 4 * half;
            sH[(wid * 32 + crow) * 136 + n * 32 + lr31] = f2bf(fmaxf(acc[n][q] + bias, 0.0f));
        }
    }
    WAVE_LDS_FENCE();

    floatx16 acc2[4];
    #pragma unroll
    for (int n = 0; n < 4; ++n)
        #pragma unroll
        for (int q = 0; q < 16; ++q) acc2[n][q] = 0.0f;
    NOPGUARD_INIT4x16(acc2);

    #pragma unroll
    for (int s = 0; s < 8; ++s) {
        *reinterpret_cast<short8*>(sW + tid * 8) = wpre;
        __syncthreads();
        if (s < 7)
            wpre = *reinterpret_cast<const short8*>(W1q + 40960 + (s + 1) * 2048 + tid * 8);
        short8 a = *reinterpret_cast<const short8*>(&sH[wrow * 136 + s * 16 + half * 8]);
        #pragma unroll
        for (int n = 0; n < 4; ++n) {
            short8 b = *reinterpret_cast<const short8*>(sW + n * 512 + lane * 8);
            acc2[n] = mfma32x32x16(a, b, acc2[n]);
        }
        __syncthreads();
    }
    NOPGUARD4x16(acc2);
    WAVE_LDS_FENCE();

    #pragma unroll
    for (int n = 0; n < 4; ++n) {
        float bias = mb2[n * 32 + lr31];
        #pragma unroll
        for (int q = 0; q < 16; ++q) {
            int crow = (q & 3) + 8 * (q >> 2) + 4 * half;
            sH[(wid * 32 + crow) * 136 + n * 32 + lr31] = f2bf(acc2[n][q] + bias);
        }
    }
    WAVE_LDS_FENCE();

    {
        unsigned int m = hm32;
        while (m) {
            int start = __ffs(m) - 1;
            unsigned int m2 = m & (m - 1);
            int end = m2 ? (__ffs(m2) - 1) : 32;
            float sum0 = 0.0f, sum1 = 0.0f;
            for (int r = start; r < end; ++r) {
                int rw = wid * 32 + r;
                unsigned int u0 = sH[rw * 136 + lane];
                unsigned int u1 = sH[rw * 136 + 64 + lane];
                sum0 += __uint_as_float(u0 << 16);
                sum1 += __uint_as_float(u1 << 16);
            }
            int d = sDst[wid * 32 + start];
            atomicAdd(&aggr[d * 128 + lane], sum0);
            atomicAdd(&aggr[d * 128 + 64 + lane], sum1);
            m = m2;
        }
    }
}

// ---------------- node update MLP + residual + LayerNorm ----------------
// Residual now from bf16 xb (rows are L1-hot from the A-fragment stream):
// drops the 25.6 MB fp32 x read; error bound ~0.004 vs fp32 residual.
__global__
void node_kernel(const unsigned short* __restrict__ xb, const float* __restrict__ aggr,
                 const unsigned short* __restrict__ U1p, const float* __restrict__ ub1,
                 const unsigned short* __restrict__ U2p, const float* __restrict__ ub2,
                 const float* __restrict__ gamma, const float* __restrict__ beta,
                 float* __restrict__ out) {
    __shared__ unsigned short sH[64 * 136];

    const int tid = threadIdx.x;
    const int lane = tid & 63;
    const int wid = tid >> 6;
    const int g = lane >> 4;
    const int lr = lane & 15;
    const int arow = wid * 16 + lr;
    const int n0 = blockIdx.x * 64;

    int nd0 = n0 + arow;
    int ndc0 = (nd0 < NN) ? nd0 : (NN - 1);

    const unsigned short* xp = xb + (size_t)ndc0 * 128 + g * 8;
    const float* ap = aggr + (size_t)ndc0 * 128 + g * 8;

    short8 af[8];
    float4 ta[8];
    #pragma unroll
    for (int kk = 0; kk < 4; ++kk) {
        af[kk] = *reinterpret_cast<const short8*>(xp + kk * 32);
        ta[2 * kk]     = *reinterpret_cast<const float4*>(ap + kk * 32);
        ta[2 * kk + 1] = *reinterpret_cast<const float4*>(ap + kk * 32 + 4);
    }
    #pragma unroll
    for (int kk = 0; kk < 4; ++kk)
        af[4 + kk] = pack2(ta[2 * kk], ta[2 * kk + 1]);

    floatx4 acc[8];
    #pragma unroll
    for (int n = 0; n < 8; ++n)
        #pragma unroll
        for (int r = 0; r < 4; ++r) acc[n][r] = 0.0f;
    NOPGUARD_INIT8(acc);

    #pragma unroll
    for (int kk = 0; kk < 8; ++kk) {
        const short8* wb = reinterpret_cast<const short8*>(U1p) + (kk * 8) * 64 + lane;
        #pragma unroll
        for (int n = 0; n < 8; ++n)
            acc[n] = mfma16x16x32(af[kk], wb[n * 64], acc[n]);
    }
    NOPGUARD8(acc);

    #pragma unroll
    for (int n = 0; n < 8; ++n) {
        float bias = ub1[n * 16 + lr];
        #pragma unroll
        for (int r = 0; r < 4; ++r) {
            int row = wid * 16 + g * 4 + r;
            sH[row * 136 + n * 16 + lr] = f2bf(fmaxf(acc[n][r] + bias, 0.0f));
        }
    }
    WAVE_LDS_FENCE();

    short8 a2[4];
    #pragma unroll
    for (int kk = 0; kk < 4; ++kk)
        a2[kk] = *reinterpret_cast<const short8*>(&sH[arow * 136 + kk * 32 + g * 8]);

    floatx4 acc2[8];
    #pragma unroll
    for (int n = 0; n < 8; ++n)
        #pragma unroll
        for (int r = 0; r < 4; ++r) acc2[n][r] = 0.0f;
    NOPGUARD_INIT8(acc2);

    #pragma unroll
    for (int kk = 0; kk < 4; ++kk) {
        const short8* wb = reinterpret_cast<const short8*>(U2p) + (kk * 8) * 64 + lane;
        #pragma unroll
        for (int n = 0; n < 8; ++n)
            acc2[n] = mfma16x16x32(a2[kk], wb[n * 64], acc2[n]);
    }
    NOPGUARD8(acc2);

    #pragma unroll
    for (int r = 0; r < 4; ++r) {
        int row = wid * 16 + g * 4 + r;
        int nd = n0 + row;
        int ndc = (nd < NN) ? nd : (NN - 1);
        float vals[8];
        float s1 = 0.0f, s2 = 0.0f;
        #pragma unroll
        for (int n = 0; n < 8; ++n) {
            int col = n * 16 + lr;
            float v = acc2[n][r] + ub2[col] + bf2f(xb[(size_t)ndc * 128 + col]);
            vals[n] = v;
            s1 += v;
            s2 += v * v;
        }
        #pragma unroll
        for (int m = 1; m < 16; m <<= 1) {
            s1 += __shfl_xor(s1, m);
            s2 += __shfl_xor(s2, m);
        }
        float mean = s1 * (1.0f / 128.0f);
        float var = s2 * (1.0f / 128.0f) - mean * mean;
        float inv = rsqrtf(var + 1e-5f);
        if (nd < NN) {
            #pragma unroll
            for (int n = 0; n < 8; ++n) {
                int col = n * 16 + lr;
                out[nd * 128 + col] = (vals[n] - mean) * inv * gamma[col] + beta[col];
            }
        }
    }
}

extern "C" void kernel_launch(void* const* d_in, const int* in_sizes, int n_in,
                              void* d_out, int out_size, void* d_ws, size_t ws_size,
                              hipStream_t stream) {
    const float* x     = (const float*)d_in[0];
    const int*   ei    = (const int*)d_in[1];
    const float* ea    = (const float*)d_in[2];
    const float* cd    = (const float*)d_in[3];
    const float* mW1   = (const float*)d_in[4];
    const float* mb1   = (const float*)d_in[5];
    const float* mW2   = (const float*)d_in[6];
    const float* mb2   = (const float*)d_in[7];
    const float* uW1   = (const float*)d_in[8];
    const float* ub1   = (const float*)d_in[9];
    const float* uW2   = (const float*)d_in[10];
    const float* ub2   = (const float*)d_in[11];
    const float* gamma = (const float*)d_in[12];
    const float* beta  = (const float*)d_in[13];
    float* out = (float*)d_out;

    char* ws = (char*)d_ws;
    unsigned short* W1q = (unsigned short*)(ws);                     // 81,920 B (W2q contiguous after)
    unsigned short* W2q = (unsigned short*)(ws + 81920);             // 32,768 B
    unsigned short* U1p = (unsigned short*)(ws + 114688);            // 65,536 B
    unsigned short* U2p = (unsigned short*)(ws + 180224);            // 32,768 B
    int* counts  = (int*)(ws + 212992);                              // 200,704 B
    int* cursor  = (int*)(ws + 413696);                              // 200,704 B (adjacent: one memset)
    int* partial = (int*)(ws + 614400);                              // 200,704 B
    unsigned long long* epack = (unsigned long long*)(ws + 815360);  // 6,400,000 B
    uint2* relb  = (uint2*)(ws + 7215360);                           // 6,400,000 B
    unsigned short* xbuf = (unsigned short*)(ws + 13615360);         // 12,800,000 B
    unsigned short* eabuf = (unsigned short*)(ws + 26415360);        // 51,200,000 B (unsorted, by eid)
    // total ws use: 77,615,360 B

    float* aggr = out;   // aggr lives in d_out (exactly NN*HD floats)

    hipMemsetAsync(counts, 0, (size_t)(614400 - 212992), stream);
    hipMemsetAsync(aggr, 0, (size_t)NN * HD * sizeof(float), stream);

    prep_kernel<<<(4106496 + 255) / 256, 256, 0, stream>>>(
        x, xbuf, ea, eabuf, ei, counts, mW1, mW2, uW1, uW2, W1q, W2q, U1p, U2p);
    scan_kernel<<<1, 1024, 0, stream>>>(counts, partial);
    scatter_kernel<<<(NE + 255) / 256, 256, 0, stream>>>(ei, partial, cursor, cd, epack, relb);
    msg_kernel<<<NE / 128, 256, 0, stream>>>(xbuf, eabuf, epack, relb, W1q, mb1, mb2, aggr);
    node_kernel<<<(NN + 63) / 64, 256, 0, stream>>>(xbuf, aggr, U1p, ub1, U2p, ub2, gamma, beta, out);
}

// Round 21
// 276.723 us; speedup vs baseline: 1.1679x; 1.1679x over previous
//
#include <hip/hip_runtime.h>

#define NN 50000
#define NE 800000
#define HD 128

typedef short short8 __attribute__((ext_vector_type(8)));
typedef float floatx4 __attribute__((ext_vector_type(4)));
typedef float floatx16 __attribute__((ext_vector_type(16)));

static __device__ __forceinline__ unsigned short f2bf(float f) {
    unsigned int u = __float_as_uint(f);
    unsigned int lsb = (u >> 16) & 1u;
    u += 0x7fffu + lsb;
    return (unsigned short)(u >> 16);
}

static __device__ __forceinline__ float bf2f(unsigned short h) {
    return __uint_as_float((unsigned int)h << 16);
}

// HW packed f32->bf16 (RNE), 2 elems/instr; lo=src0, hi=src1.
static __device__ __forceinline__ short8 pack2(float4 a, float4 b) {
    union { unsigned int u[4]; short8 s; } r;
    asm("v_cvt_pk_bf16_f32 %0, %1, %2" : "=v"(r.u[0]) : "v"(a.x), "v"(a.y));
    asm("v_cvt_pk_bf16_f32 %0, %1, %2" : "=v"(r.u[1]) : "v"(a.z), "v"(a.w));
    asm("v_cvt_pk_bf16_f32 %0, %1, %2" : "=v"(r.u[2]) : "v"(b.x), "v"(b.y));
    asm("v_cvt_pk_bf16_f32 %0, %1, %2" : "=v"(r.u[3]) : "v"(b.z), "v"(b.w));
    return r.s;
}

static __device__ __forceinline__ floatx4 mfma16x16x32(short8 a, short8 b, floatx4 c) {
    asm("v_mfma_f32_16x16x32_bf16 %0, %1, %2, %0" : "+v"(c) : "v"(a), "v"(b));
    return c;
}

static __device__ __forceinline__ floatx16 mfma32x32x16(short8 a, short8 b, floatx16 c) {
    asm("v_mfma_f32_32x32x16_bf16 %0, %1, %2, %0" : "+v"(c) : "v"(a), "v"(b));
    return c;
}

// Hazard guards: inline-asm MFMA is invisible to LLVM's GCNHazardRecognizer.
#define NOPGUARD_INIT8(A) asm volatile("s_nop 3" \
  : "+v"(A[0]),"+v"(A[1]),"+v"(A[2]),"+v"(A[3]),"+v"(A[4]),"+v"(A[5]),"+v"(A[6]),"+v"(A[7]))
#define NOPGUARD8(A) asm volatile("s_nop 7\ns_nop 7" \
  : "+v"(A[0]),"+v"(A[1]),"+v"(A[2]),"+v"(A[3]),"+v"(A[4]),"+v"(A[5]),"+v"(A[6]),"+v"(A[7]))
#define NOPGUARD_INIT4x16(A) asm volatile("s_nop 7" \
  : "+v"(A[0]),"+v"(A[1]),"+v"(A[2]),"+v"(A[3]))
#define NOPGUARD4x16(A) asm volatile("s_nop 7\ns_nop 7\ns_nop 7" \
  : "+v"(A[0]),"+v"(A[1]),"+v"(A[2]),"+v"(A[3]))

// Wave-local LDS fence.
#define WAVE_LDS_FENCE() asm volatile("s_waitcnt lgkmcnt(0)" ::: "memory")

// ---------------- fused prep: x-cast + hist + ea-cast + weight packing ----------------
__global__ void prep_kernel(const float* __restrict__ x, unsigned short* __restrict__ xbuf,
                            const float* __restrict__ ea, unsigned short* __restrict__ eabuf,
                            const int* __restrict__ ei, int* __restrict__ counts,
                            const float* __restrict__ mW1, const float* __restrict__ mW2,
                            const float* __restrict__ uW1, const float* __restrict__ uW2,
                            unsigned short* __restrict__ W1q, unsigned short* __restrict__ W2q,
                            unsigned short* __restrict__ U1p, unsigned short* __restrict__ U2p) {
    int t = blockIdx.x * 256 + threadIdx.x;
    if (t < 800000) {
        float4 a = *reinterpret_cast<const float4*>(x + (size_t)t * 8);
        float4 b = *reinterpret_cast<const float4*>(x + (size_t)t * 8 + 4);
        *reinterpret_cast<short8*>(xbuf + (size_t)t * 8) = pack2(a, b);
        atomicAdd(&counts[ei[NE + t]], 1);
    } else if (t < 4000000) {
        int u = t - 800000;
        float4 a = *reinterpret_cast<const float4*>(ea + (size_t)u * 8);
        float4 b = *reinterpret_cast<const float4*>(ea + (size_t)u * 8 + 4);
        *reinterpret_cast<short8*>(eabuf + (size_t)u * 8) = pack2(a, b);
    } else {
        int w = t - 4000000;
        if (w < 40960) {
            int i = w;
            int j = i & 7, lane = (i >> 3) & 63, n = (i >> 9) & 3, s = i >> 11;
            int k = s * 16 + ((lane >> 5) << 3) + j;
            int c = n * 32 + (lane & 31);
            W1q[i] = f2bf((k < 291) ? mW1[k * 128 + c] : 0.0f);
        } else if (w < 57344) {
            int i = w - 40960;
            int j = i & 7, lane = (i >> 3) & 63, n = (i >> 9) & 3, s = i >> 11;
            int k = s * 16 + ((lane >> 5) << 3) + j;
            int c = n * 32 + (lane & 31);
            W2q[i] = f2bf(mW2[k * 128 + c]);
        } else if (w < 90112) {
            int i = w - 57344;
            int j = i & 7, lane = (i >> 3) & 63, n = (i >> 9) & 7, kk = i >> 12;
            int k = kk * 32 + ((lane >> 4) << 3) + j;
            int c = n * 16 + (lane & 15);
            U1p[i] = f2bf(uW1[k * 128 + c]);
        } else if (w < 106496) {
            int i = w - 90112;
            int j = i & 7, lane = (i >> 3) & 63, n = (i >> 9) & 7, kk = i >> 12;
            int k = kk * 32 + ((lane >> 4) << 3) + j;
            int c = n * 16 + (lane & 15);
            U2p[i] = f2bf(uW2[k * 128 + c]);
        }
    }
}

// ---------------- CSR scan: two-phase (parallel), r19-proven ----------------
__global__ __launch_bounds__(1024)
void scan1_kernel(const int* __restrict__ counts, int* __restrict__ partial,
                  int* __restrict__ bsum) {
    __shared__ int wsum[16];
    int tid = threadIdx.x;
    int gid = blockIdx.x * 1024 + tid;
    int lane = tid & 63, w = tid >> 6;
    int v = (gid < NN) ? counts[gid] : 0;
    int s = v;
    #pragma unroll
    for (int o = 1; o < 64; o <<= 1) { int t = __shfl_up(s, o); if (lane >= o) s += t; }
    if (lane == 63) wsum[w] = s;
    __syncthreads();
    if (w == 0 && lane < 16) {
        int t = wsum[lane];
        #pragma unroll
        for (int o = 1; o < 16; o <<= 1) { int u = __shfl_up(t, o); if (lane >= o) t += u; }
        wsum[lane] = t;
    }
    __syncthreads();
    int base = (w > 0) ? wsum[w - 1] : 0;
    if (gid < NN) partial[gid] = base + s - v;
    if (tid == 1023) bsum[blockIdx.x] = base + s;
}

__global__ void scan2_kernel(int* __restrict__ bsum, int n) {
    int lane = threadIdx.x;
    int v = (lane < n) ? bsum[lane] : 0;
    int s = v;
    #pragma unroll
    for (int o = 1; o < 64; o <<= 1) { int t = __shfl_up(s, o); if (lane >= o) s += t; }
    if (lane < n) bsum[lane] = s - v;
}

// ---------------- scatter: epack64 (eid|src<<20|dst<<36) + bf16 rel ----------------
__global__ void scatter_kernel(const int* __restrict__ ei, const int* __restrict__ partial,
                               const int* __restrict__ bsum, int* __restrict__ cursor,
                               const float* __restrict__ cd,
                               unsigned long long* __restrict__ epack,
                               uint2* __restrict__ relb) {
    int e = blockIdx.x * 256 + threadIdx.x;
    if (e < NE) {
        int d = ei[NE + e];
        int s = ei[e];
        int pos = partial[d] + bsum[d >> 10] + atomicAdd(&cursor[d], 1);
        epack[pos] = (unsigned long long)e
                   | ((unsigned long long)s << 20)
                   | ((unsigned long long)d << 36);
        float r0 = cd[d * 3 + 0] - cd[s * 3 + 0];
        float r1 = cd[d * 3 + 1] - cd[s * 3 + 1];
        float r2 = cd[d * 3 + 2] - cd[s * 3 + 2];
        uint2 rr;
        asm("v_cvt_pk_bf16_f32 %0, %1, %2" : "=v"(rr.x) : "v"(r0), "v"(r1));
        asm("v_cvt_pk_bf16_f32 %0, %1, %2" : "=v"(rr.y) : "v"(r2), "v"(0.0f));
        relb[pos] = rr;
    }
}

// ---------------- message MLP (unchanged: 160us, at its ledgered floor) ----------------
__global__ __launch_bounds__(256, 4)
void msg_kernel(const unsigned short* __restrict__ xb, const unsigned short* __restrict__ eab,
                const unsigned long long* __restrict__ epack, const uint2* __restrict__ relb,
                const unsigned short* __restrict__ W1q, const float* __restrict__ mb1,
                const float* __restrict__ mb2,
                float* __restrict__ aggr) {
    __shared__ unsigned short sH[128 * 136];   // hidden tile, then bf16 out tile
    __shared__ unsigned short sW[2048];        // one 4 KB weight chunk
    __shared__ int sDst[128];

    const int tid = threadIdx.x;
    const int lane = tid & 63;
    const int wid = tid >> 6;
    const int lr31 = lane & 31;
    const int half = lane >> 5;
    const int wrow = wid * 32 + lr31;
    const int eidx = blockIdx.x * 128 + wrow;

    const unsigned long long p = epack[eidx];
    const int eid = (int)(p & 0xFFFFFull);
    const int src = (int)((p >> 20) & 0xFFFFull);
    const int dst = (int)(p >> 36);
    if (half == 0) sDst[wrow] = dst;

    const unsigned short* xs = xb + (size_t)src * 128 + half * 8;
    const unsigned short* xd = xb + (size_t)dst * 128 + half * 8;
    const unsigned short* epr = eab + (size_t)eid * 32 + half * 8;
    const uint2 rr = relb[eidx];

    // Prefetch weight chunk 0 (W2 chunks contiguous at short-offset 40960).
    short8 wpre = *reinterpret_cast<const short8*>(W1q + tid * 8);

    floatx16 acc[4];
    #pragma unroll
    for (int n = 0; n < 4; ++n)
        #pragma unroll
        for (int q = 0; q < 16; ++q) acc[n][q] = 0.0f;
    NOPGUARD_INIT4x16(acc);

    #pragma unroll
    for (int s = 0; s < 19; ++s) {
        *reinterpret_cast<short8*>(sW + tid * 8) = wpre;
        __syncthreads();
        {
            int nc = (s < 18) ? (s + 1) * 2048 : 40960;
            wpre = *reinterpret_cast<const short8*>(W1q + nc + tid * 8);
        }
        short8 a;
        if (s < 8) {
            a = *reinterpret_cast<const short8*>(xs + s * 16);
        } else if (s < 16) {
            a = *reinterpret_cast<const short8*>(xd + (s - 8) * 16);
        } else if (s < 18) {
            a = *reinterpret_cast<const short8*>(epr + (s - 16) * 16);
        } else {
            union { unsigned int u[4]; short8 s8; } a9;
            a9.u[0] = (half == 0) ? rr.x : 0u;
            a9.u[1] = (half == 0) ? rr.y : 0u;
            a9.u[2] = 0u; a9.u[3] = 0u;
            a = a9.s8;
        }
        #pragma unroll
        for (int n = 0; n < 4; ++n) {
            short8 b = *reinterpret_cast<const short8*>(sW + n * 512 + lane * 8);
            acc[n] = mfma32x32x16(a, b, acc[n]);
        }
        __syncthreads();
    }
    NOPGUARD4x16(acc);

    unsigned int hm32;
    {
        bool head = false;
        if (lane < 32) {
            int r = wid * 32 + lane;
            head = (lane == 0) || (sDst[r] != sDst[r - 1]);
        }
        unsigned long long m = __ballot(head);
        hm32 = (unsigned int)(m & 0xFFFFFFFFull);
    }

    #pragma unroll
    for (int n = 0; n < 4; ++n) {
        float bias = mb1[n * 32 + lr31];
        #pragma unroll
        for (int q = 0; q < 16; ++q) {
            int crow = (q & 3) + 8 * (q >> 2) + 4 * half;
            sH[(wid * 32 + crow) * 136 + n * 32 + lr31] = f2bf(fmaxf(acc[n][q] + bias, 0.0f));
        }
    }
    WAVE_LDS_FENCE();

    floatx16 acc2[4];
    #pragma unroll
    for (int n = 0; n < 4; ++n)
        #pragma unroll
        for (int q = 0; q < 16; ++q) acc2[n][q] = 0.0f;
    NOPGUARD_INIT4x16(acc2);

    #pragma unroll
    for (int s = 0; s < 8; ++s) {
        *reinterpret_cast<short8*>(sW + tid * 8) = wpre;
        __syncthreads();
        if (s < 7)
            wpre = *reinterpret_cast<const short8*>(W1q + 40960 + (s + 1) * 2048 + tid * 8);
        short8 a = *reinterpret_cast<const short8*>(&sH[wrow * 136 + s * 16 + half * 8]);
        #pragma unroll
        for (int n = 0; n < 4; ++n) {
            short8 b = *reinterpret_cast<const short8*>(sW + n * 512 + lane * 8);
            acc2[n] = mfma32x32x16(a, b, acc2[n]);
        }
        __syncthreads();
    }
    NOPGUARD4x16(acc2);
    WAVE_LDS_FENCE();

    #pragma unroll
    for (int n = 0; n < 4; ++n) {
        float bias = mb2[n * 32 + lr31];
        #pragma unroll
        for (int q = 0; q < 16; ++q) {
            int crow = (q & 3) + 8 * (q >> 2) + 4 * half;
            sH[(wid * 32 + crow) * 136 + n * 32 + lr31] = f2bf(acc2[n][q] + bias);
        }
    }
    WAVE_LDS_FENCE();

    {
        unsigned int m = hm32;
        while (m) {
            int start = __ffs(m) - 1;
            unsigned int m2 = m & (m - 1);
            int end = m2 ? (__ffs(m2) - 1) : 32;
            float sum0 = 0.0f, sum1 = 0.0f;
            for (int r = start; r < end; ++r) {
                int rw = wid * 32 + r;
                unsigned int u0 = sH[rw * 136 + lane];
                unsigned int u1 = sH[rw * 136 + 64 + lane];
                sum0 += __uint_as_float(u0 << 16);
                sum1 += __uint_as_float(u1 << 16);
            }
            int d = sDst[wid * 32 + start];
            atomicAdd(&aggr[d * 128 + lane], sum0);
            atomicAdd(&aggr[d * 128 + 64 + lane], sum1);
            m = m2;
        }
    }
}

// ---------------- node update MLP + residual(bf16) + LayerNorm ----------------
__global__
void node_kernel(const unsigned short* __restrict__ xb, const float* __restrict__ aggr,
                 const unsigned short* __restrict__ U1p, const float* __restrict__ ub1,
                 const unsigned short* __restrict__ U2p, const float* __restrict__ ub2,
                 const float* __restrict__ gamma, const float* __restrict__ beta,
                 float* __restrict__ out) {
    __shared__ unsigned short sH[64 * 136];

    const int tid = threadIdx.x;
    const int lane = tid & 63;
    const int wid = tid >> 6;
    const int g = lane >> 4;
    const int lr = lane & 15;
    const int arow = wid * 16 + lr;
    const int n0 = blockIdx.x * 64;

    int nd0 = n0 + arow;
    int ndc0 = (nd0 < NN) ? nd0 : (NN - 1);

    const unsigned short* xp = xb + (size_t)ndc0 * 128 + g * 8;
    const float* ap = aggr + (size_t)ndc0 * 128 + g * 8;

    short8 af[8];
    float4 ta[8];
    #pragma unroll
    for (int kk = 0; kk < 4; ++kk) {
        af[kk] = *reinterpret_cast<const short8*>(xp + kk * 32);
        ta[2 * kk]     = *reinterpret_cast<const float4*>(ap + kk * 32);
        ta[2 * kk + 1] = *reinterpret_cast<const float4*>(ap + kk * 32 + 4);
    }
    #pragma unroll
    for (int kk = 0; kk < 4; ++kk)
        af[4 + kk] = pack2(ta[2 * kk], ta[2 * kk + 1]);

    floatx4 acc[8];
    #pragma unroll
    for (int n = 0; n < 8; ++n)
        #pragma unroll
        for (int r = 0; r < 4; ++r) acc[n][r] = 0.0f;
    NOPGUARD_INIT8(acc);

    #pragma unroll
    for (int kk = 0; kk < 8; ++kk) {
        const short8* wb = reinterpret_cast<const short8*>(U1p) + (kk * 8) * 64 + lane;
        #pragma unroll
        for (int n = 0; n < 8; ++n)
            acc[n] = mfma16x16x32(af[kk], wb[n * 64], acc[n]);
    }
    NOPGUARD8(acc);

    #pragma unroll
    for (int n = 0; n < 8; ++n) {
        float bias = ub1[n * 16 + lr];
        #pragma unroll
        for (int r = 0; r < 4; ++r) {
            int row = wid * 16 + g * 4 + r;
            sH[row * 136 + n * 16 + lr] = f2bf(fmaxf(acc[n][r] + bias, 0.0f));
        }
    }
    WAVE_LDS_FENCE();

    short8 a2[4];
    #pragma unroll
    for (int kk = 0; kk < 4; ++kk)
        a2[kk] = *reinterpret_cast<const short8*>(&sH[arow * 136 + kk * 32 + g * 8]);

    floatx4 acc2[8];
    #pragma unroll
    for (int n = 0; n < 8; ++n)
        #pragma unroll
        for (int r = 0; r < 4; ++r) acc2[n][r] = 0.0f;
    NOPGUARD_INIT8(acc2);

    #pragma unroll
    for (int kk = 0; kk < 4; ++kk) {
        const short8* wb = reinterpret_cast<const short8*>(U2p) + (kk * 8) * 64 + lane;
        #pragma unroll
        for (int n = 0; n < 8; ++n)
            acc2[n] = mfma16x16x32(a2[kk], wb[n * 64], acc2[n]);
    }
    NOPGUARD8(acc2);

    #pragma unroll
    for (int r = 0; r < 4; ++r) {
        int row = wid * 16 + g * 4 + r;
        int nd = n0 + row;
        int ndc = (nd < NN) ? nd : (NN - 1);
        float vals[8];
        float s1 = 0.0f, s2 = 0.0f;
        #pragma unroll
        for (int n = 0; n < 8; ++n) {
            int col = n * 16 + lr;
            float v = acc2[n][r] + ub2[col] + bf2f(xb[(size_t)ndc * 128 + col]);
            vals[n] = v;
            s1 += v;
            s2 += v * v;
        }
        #pragma unroll
        for (int m = 1; m < 16; m <<= 1) {
            s1 += __shfl_xor(s1, m);
            s2 += __shfl_xor(s2, m);
        }
        float mean = s1 * (1.0f / 128.0f);
        float var = s2 * (1.0f / 128.0f) - mean * mean;
        float inv = rsqrtf(var + 1e-5f);
        if (nd < NN) {
            #pragma unroll
            for (int n = 0; n < 8; ++n) {
                int col = n * 16 + lr;
                out[nd * 128 + col] = (vals[n] - mean) * inv * gamma[col] + beta[col];
            }
        }
    }
}

extern "C" void kernel_launch(void* const* d_in, const int* in_sizes, int n_in,
                              void* d_out, int out_size, void* d_ws, size_t ws_size,
                              hipStream_t stream) {
    const float* x     = (const float*)d_in[0];
    const int*   ei    = (const int*)d_in[1];
    const float* ea    = (const float*)d_in[2];
    const float* cd    = (const float*)d_in[3];
    const float* mW1   = (const float*)d_in[4];
    const float* mb1   = (const float*)d_in[5];
    const float* mW2   = (const float*)d_in[6];
    const float* mb2   = (const float*)d_in[7];
    const float* uW1   = (const float*)d_in[8];
    const float* ub1   = (const float*)d_in[9];
    const float* uW2   = (const float*)d_in[10];
    const float* ub2   = (const float*)d_in[11];
    const float* gamma = (const float*)d_in[12];
    const float* beta  = (const float*)d_in[13];
    float* out = (float*)d_out;

    char* ws = (char*)d_ws;
    unsigned short* W1q = (unsigned short*)(ws);                     // 81,920 B (W2q contiguous after)
    unsigned short* W2q = (unsigned short*)(ws + 81920);             // 32,768 B
    unsigned short* U1p = (unsigned short*)(ws + 114688);            // 65,536 B
    unsigned short* U2p = (unsigned short*)(ws + 180224);            // 32,768 B
    int* counts  = (int*)(ws + 212992);                              // 200,704 B
    int* cursor  = (int*)(ws + 413696);                              // 200,704 B (adjacent: one memset)
    int* partial = (int*)(ws + 614400);                              // 200,704 B
    int* bsum    = (int*)(ws + 815104);                              // 256 B
    unsigned long long* epack = (unsigned long long*)(ws + 815360);  // 6,400,000 B
    uint2* relb  = (uint2*)(ws + 7215360);                           // 6,400,000 B
    unsigned short* xbuf = (unsigned short*)(ws + 13615360);         // 12,800,000 B
    unsigned short* eabuf = (unsigned short*)(ws + 26415360);        // 51,200,000 B (unsorted, by eid)
    // total ws use: 77,615,360 B

    float* aggr = out;   // aggr lives in d_out (exactly NN*HD floats)

    hipMemsetAsync(counts, 0, (size_t)(614400 - 212992), stream);
    hipMemsetAsync(aggr, 0, (size_t)NN * HD * sizeof(float), stream);

    prep_kernel<<<(4106496 + 255) / 256, 256, 0, stream>>>(
        x, xbuf, ea, eabuf, ei, counts, mW1, mW2, uW1, uW2, W1q, W2q, U1p, U2p);
    scan1_kernel<<<(NN + 1023) / 1024, 1024, 0, stream>>>(counts, partial, bsum);
    scan2_kernel<<<1, 64, 0, stream>>>(bsum, (NN + 1023) / 1024);
    scatter_kernel<<<(NE + 255) / 256, 256, 0, stream>>>(ei, partial, bsum, cursor, cd, epack, relb);
    msg_kernel<<<NE / 128, 256, 0, stream>>>(xbuf, eabuf, epack, relb, W1q, mb1, mb2, aggr);
    node_kernel<<<(NN + 63) / 64, 256, 0, stream>>>(xbuf, aggr, U1p, ub1, U2p, ub2, gamma, beta, out);
}